// Round 10
// baseline (44.639 us; speedup 1.0000x reference)
//
#include <hip/hip_runtime.h>

constexpr int THREADS = 256;   // known-good codegen (R3/R7); 512 regressed (R4)
constexpr int BLOCKS  = 512;   // best measured (R7); 1024/1954 slightly worse
constexpr int WAVES   = THREADS / 64;

// R4-R6 lesson: ticket atomicAdd fusion serializes ~38ns/block at the point
// of coherence (8 non-coherent XCD L2s). THIS kernel fuses via parallel
// flag release-stores + a single spinning block (no RMW serialization).
// R7/R8/R9 lesson: main loop is at the ~5 TB/s pattern ceiling; TLP/ILP flat.

#define NLOG2E -1.44269504088896340f
// alpha_t * ln2 constants: loss_term = (alpha_t*ln2) * (1-pt)^2 * log2(1/pt)
#define C_TM1   0.17328679513998632f   /* 0.25 * ln2 */
#define C_TM0   0.51986038541995900f   /* 0.75 * ln2 */

// CORAL focal term, algebraically reduced:
//   pt = sigmoid(y), y = tm ? x : -x ; e = exp(-y); d = 1+e
//   pt = 1/d ; 1-pt = e/d ; -ln(pt) = ln(d) = ln2*log2(d)
//   loss = alpha_t*(1-pt)^2*(-ln(pt)) = (alpha_t*ln2)*(e/d)^2*log2(d)
__device__ __forceinline__ float coral_term(float x, bool tm) {
    float y  = tm ? x : -x;
    float e  = __builtin_amdgcn_exp2f(y * NLOG2E);   // exp(-y)
    float d  = 1.0f + e;
    float r  = __builtin_amdgcn_rcpf(d);             // pt
    float om = e * r;                                 // 1 - pt
    float L  = __builtin_amdgcn_logf(d);              // log2(d) >= 0
    float w  = tm ? C_TM1 : C_TM0;
    return om * om * w * L;
}

__device__ __forceinline__ void do_sample(
        float kx, float ky, float kz, float kw,
        float ma, float mb, float mc,
        float la, float lb, float lc,
        int kt, int mt, int lt, float w,
        float& s0, float& s1, float& s2) {
    float a = coral_term(kx, 0 < kt) + coral_term(ky, 1 < kt)
            + coral_term(kz, 2 < kt) + coral_term(kw, 3 < kt);
    s0 = fmaf(w, a, s0);
    float b = coral_term(ma, 0 < mt) + coral_term(mb, 1 < mt)
            + coral_term(mc, 2 < mt);
    s1 = fmaf(w, b, s1);
    float c = coral_term(la, 0 < lt) + coral_term(lb, 1 < lt)
            + coral_term(lc, 2 < lt);
    s2 = fmaf(w, c, s2);
}

__global__ __launch_bounds__(THREADS) void coral_fused(
        const float* __restrict__ kl_logits,
        const float* __restrict__ jsnm_logits,
        const float* __restrict__ jsnl_logits,
        const float* __restrict__ cw,
        const int*   __restrict__ kl_t,
        const int*   __restrict__ jsnm_t,
        const int*   __restrict__ jsnl_t,
        float*       __restrict__ partials,   // [nblocks*3] AoS (R7 layout)
        unsigned*    __restrict__ flags,      // [nblocks]; ==1 means ready
        float*       __restrict__ out,
        int n, int ngroups, float fn) {
    // class weights staged in LDS: 5 words in 5 distinct banks ->
    // per-lane dynamic gather is conflict-free multicast
    __shared__ float lw[8];
    if (threadIdx.x < 5) lw[threadIdx.x] = cw[threadIdx.x];
    __syncthreads();

    float s0 = 0.0f, s1 = 0.0f, s2 = 0.0f;

    const int stride = gridDim.x * THREADS;
    const float4* kl4 = reinterpret_cast<const float4*>(kl_logits);
    const float4* m4  = reinterpret_cast<const float4*>(jsnm_logits);
    const float4* l4  = reinterpret_cast<const float4*>(jsnl_logits);
    const int4*   kt4 = reinterpret_cast<const int4*>(kl_t);
    const int4*   mt4 = reinterpret_cast<const int4*>(jsnm_t);
    const int4*   lt4 = reinterpret_cast<const int4*>(jsnl_t);

    for (int g = blockIdx.x * THREADS + threadIdx.x; g < ngroups; g += stride) {
        const int4 kt = kt4[g];
        const int4 mt = mt4[g];
        const int4 lt = lt4[g];
        const float wx = lw[kt.x];
        const float wy = lw[kt.y];
        const float wz = lw[kt.z];
        const float ww = lw[kt.w];

        const float4 k0 = kl4[4 * g + 0];
        const float4 k1 = kl4[4 * g + 1];
        const float4 k2 = kl4[4 * g + 2];
        const float4 k3 = kl4[4 * g + 3];
        const float4 m0 = m4[3 * g + 0];
        const float4 m1 = m4[3 * g + 1];
        const float4 m2 = m4[3 * g + 2];
        const float4 l0 = l4[3 * g + 0];
        const float4 l1 = l4[3 * g + 1];
        const float4 l2 = l4[3 * g + 2];

        do_sample(k0.x, k0.y, k0.z, k0.w, m0.x, m0.y, m0.z, l0.x, l0.y, l0.z,
                  kt.x, mt.x, lt.x, wx, s0, s1, s2);
        do_sample(k1.x, k1.y, k1.z, k1.w, m0.w, m1.x, m1.y, l0.w, l1.x, l1.y,
                  kt.y, mt.y, lt.y, wy, s0, s1, s2);
        do_sample(k2.x, k2.y, k2.z, k2.w, m1.z, m1.w, m2.x, l1.z, l1.w, l2.x,
                  kt.z, mt.z, lt.z, wz, s0, s1, s2);
        do_sample(k3.x, k3.y, k3.z, k3.w, m2.y, m2.z, m2.w, l2.y, l2.z, l2.w,
                  kt.w, mt.w, lt.w, ww, s0, s1, s2);
    }

    // scalar tail (n % 4 samples; zero iterations when N % 4 == 0)
    const int tail_base = ngroups << 2;
    for (int i = tail_base + blockIdx.x * THREADS + threadIdx.x; i < n;
         i += stride) {
        do_sample(kl_logits[4 * i], kl_logits[4 * i + 1], kl_logits[4 * i + 2],
                  kl_logits[4 * i + 3],
                  jsnm_logits[3 * i], jsnm_logits[3 * i + 1], jsnm_logits[3 * i + 2],
                  jsnl_logits[3 * i], jsnl_logits[3 * i + 1], jsnl_logits[3 * i + 2],
                  kl_t[i], jsnm_t[i], jsnl_t[i], lw[kl_t[i]], s0, s1, s2);
    }

    // wave reduction (64 lanes)
    #pragma unroll
    for (int off = 32; off > 0; off >>= 1) {
        s0 += __shfl_xor(s0, off);
        s1 += __shfl_xor(s1, off);
        s2 += __shfl_xor(s2, off);
    }

    __shared__ float red[3][WAVES];
    const int lane = threadIdx.x & 63;
    const int wid  = threadIdx.x >> 6;
    if (lane == 0) {
        red[0][wid] = s0;
        red[1][wid] = s1;
        red[2][wid] = s2;
    }
    __syncthreads();
    if (threadIdx.x == 0) {
        float t0 = 0.0f, t1 = 0.0f, t2 = 0.0f;
        #pragma unroll
        for (int wv = 0; wv < WAVES; ++wv) {
            t0 += red[0][wv];
            t1 += red[1][wv];
            t2 += red[2][wv];
        }
        partials[blockIdx.x * 3 + 0] = t0;
        partials[blockIdx.x * 3 + 1] = t1;
        partials[blockIdx.x * 3 + 2] = t2;
        __threadfence();  // make partials visible before the ready flag
        __hip_atomic_store(&flags[blockIdx.x], 1u, __ATOMIC_RELEASE,
                           __HIP_MEMORY_SCOPE_AGENT);
    }

    // Only the LAST-ISSUED block finalizes (it finishes last -> minimal spin).
    // One release-store per block, zero RMW contention (vs R4-R6 ticket).
    if (blockIdx.x != gridDim.x - 1) return;

    const int nblocks = gridDim.x;
    for (int i = threadIdx.x; i < nblocks; i += THREADS) {
        while (__hip_atomic_load(&flags[i], __ATOMIC_ACQUIRE,
                                 __HIP_MEMORY_SCOPE_AGENT) != 1u) { }
    }
    __syncthreads();  // all flags seen -> all partials visible

    // deterministic final reduction: fixed ascending index order
    float f0 = 0.0f, f1 = 0.0f, f2 = 0.0f;
    for (int i = threadIdx.x; i < nblocks; i += THREADS) {
        f0 += partials[3 * i + 0];
        f1 += partials[3 * i + 1];
        f2 += partials[3 * i + 2];
    }
    #pragma unroll
    for (int off = 32; off > 0; off >>= 1) {
        f0 += __shfl_xor(f0, off);
        f1 += __shfl_xor(f1, off);
        f2 += __shfl_xor(f2, off);
    }
    if (lane == 0) {
        red[0][wid] = f0;
        red[1][wid] = f1;
        red[2][wid] = f2;
    }
    __syncthreads();
    if (threadIdx.x == 0) {
        float t0 = 0.0f, t1 = 0.0f, t2 = 0.0f;
        #pragma unroll
        for (int wv = 0; wv < WAVES; ++wv) {
            t0 += red[0][wv];
            t1 += red[1][wv];
            t2 += red[2][wv];
        }
        const float l_kl   = t0 / (fn * 4.0f);
        const float l_jsnm = t1 / (fn * 3.0f);
        const float l_jsnl = t2 / (fn * 3.0f);
        out[0] = (l_kl + l_jsnm + l_jsnl) / 3.0f;
        out[1] = l_kl;
        out[2] = l_jsnm;
        out[3] = l_jsnl;
    }
    __syncthreads();
    // reset flags to 0 for the next graph replay (poll is ==1, so the
    // first-call 0xAA poison is also harmless). No memset node needed.
    for (int i = threadIdx.x; i < nblocks; i += THREADS) {
        __hip_atomic_store(&flags[i], 0u, __ATOMIC_RELAXED,
                           __HIP_MEMORY_SCOPE_AGENT);
    }
}

extern "C" void kernel_launch(void* const* d_in, const int* in_sizes, int n_in,
                              void* d_out, int out_size, void* d_ws, size_t ws_size,
                              hipStream_t stream) {
    const float* kl_logits   = (const float*)d_in[0];
    const float* jsnm_logits = (const float*)d_in[1];
    const float* jsnl_logits = (const float*)d_in[2];
    const float* cw          = (const float*)d_in[3];
    const int*   kl_t        = (const int*)d_in[4];
    const int*   jsnm_t      = (const int*)d_in[5];
    const int*   jsnl_t     = (const int*)d_in[6];
    const int n = in_sizes[4];  // kl_t element count == N

    const int ngroups = n >> 2;
    int blocks = BLOCKS;
    int max_blocks = (ngroups + THREADS - 1) / THREADS;
    if (blocks > max_blocks) blocks = max_blocks;
    if (blocks < 1) blocks = 1;

    float*    partials = (float*)d_ws;                       // blocks*3 floats
    unsigned* flags    = (unsigned*)((char*)d_ws + 8192);    // blocks words
    float*    out      = (float*)d_out;

    coral_fused<<<blocks, THREADS, 0, stream>>>(
        kl_logits, jsnm_logits, jsnl_logits, cw, kl_t, jsnm_t, jsnl_t,
        partials, flags, out, n, ngroups, (float)n);
}

// Round 11
// 25.751 us; speedup vs baseline: 1.7335x; 1.7335x over previous
//
#include <hip/hip_runtime.h>

constexpr int THREADS = 256;   // 256: known-good codegen (R3/R7). 512 regressed (R4).
constexpr int BLOCKS  = 512;   // best measured (R7); 1024/1954 slightly worse
constexpr int WAVES   = THREADS / 64;

// R4-R6/R10 lesson: ANY single-kernel fused finalize (ticket atomicAdd,
// flag release-store + spin, even with sched_barrier-forced VGPR) poisons
// the main-loop codegen (VGPR collapse / serialized loads) -> 44-89us.
// Two kernels = 25.8us. Do not re-attempt fusion on this compiler/chip.
// R7/R8/R9 lesson: main loop is at the ~5 TB/s 7-stream pattern ceiling;
// TLP (512/1024/1954 blocks) and ILP (2x unroll) all flat.

#define NLOG2E -1.44269504088896340f
// alpha_t * ln2 constants: loss_term = (alpha_t*ln2) * (1-pt)^2 * log2(1/pt)
#define C_TM1   0.17328679513998632f   /* 0.25 * ln2 */
#define C_TM0   0.51986038541995900f   /* 0.75 * ln2 */

// CORAL focal term, algebraically reduced:
//   pt = sigmoid(y), y = tm ? x : -x ; e = exp(-y); d = 1+e
//   pt = 1/d ; 1-pt = e/d ; -ln(pt) = ln(d) = ln2*log2(d)
//   loss = alpha_t*(1-pt)^2*(-ln(pt)) = (alpha_t*ln2)*(e/d)^2*log2(d)
__device__ __forceinline__ float coral_term(float x, bool tm) {
    float y  = tm ? x : -x;
    float e  = __builtin_amdgcn_exp2f(y * NLOG2E);   // exp(-y)
    float d  = 1.0f + e;
    float r  = __builtin_amdgcn_rcpf(d);             // pt
    float om = e * r;                                 // 1 - pt
    float L  = __builtin_amdgcn_logf(d);              // log2(d) >= 0
    float w  = tm ? C_TM1 : C_TM0;
    return om * om * w * L;
}

__device__ __forceinline__ void do_sample(
        float kx, float ky, float kz, float kw,
        float ma, float mb, float mc,
        float la, float lb, float lc,
        int kt, int mt, int lt, float w,
        float& s0, float& s1, float& s2) {
    float a = coral_term(kx, 0 < kt) + coral_term(ky, 1 < kt)
            + coral_term(kz, 2 < kt) + coral_term(kw, 3 < kt);
    s0 = fmaf(w, a, s0);
    float b = coral_term(ma, 0 < mt) + coral_term(mb, 1 < mt)
            + coral_term(mc, 2 < mt);
    s1 = fmaf(w, b, s1);
    float c = coral_term(la, 0 < lt) + coral_term(lb, 1 < lt)
            + coral_term(lc, 2 < lt);
    s2 = fmaf(w, c, s2);
}

__global__ __launch_bounds__(THREADS) void coral_main(
        const float* __restrict__ kl_logits,
        const float* __restrict__ jsnm_logits,
        const float* __restrict__ jsnl_logits,
        const float* __restrict__ cw,
        const int*   __restrict__ kl_t,
        const int*   __restrict__ jsnm_t,
        const int*   __restrict__ jsnl_t,
        float*       __restrict__ partials,
        int n, int ngroups) {
    // class weights staged in LDS: 5 words in 5 distinct banks ->
    // per-lane dynamic gather is conflict-free multicast
    __shared__ float lw[8];
    if (threadIdx.x < 5) lw[threadIdx.x] = cw[threadIdx.x];
    __syncthreads();

    float s0 = 0.0f, s1 = 0.0f, s2 = 0.0f;

    const int stride = gridDim.x * THREADS;
    const float4* kl4 = reinterpret_cast<const float4*>(kl_logits);
    const float4* m4  = reinterpret_cast<const float4*>(jsnm_logits);
    const float4* l4  = reinterpret_cast<const float4*>(jsnl_logits);
    const int4*   kt4 = reinterpret_cast<const int4*>(kl_t);
    const int4*   mt4 = reinterpret_cast<const int4*>(jsnm_t);
    const int4*   lt4 = reinterpret_cast<const int4*>(jsnl_t);

    for (int g = blockIdx.x * THREADS + threadIdx.x; g < ngroups; g += stride) {
        const int4 kt = kt4[g];
        const int4 mt = mt4[g];
        const int4 lt = lt4[g];
        const float wx = lw[kt.x];
        const float wy = lw[kt.y];
        const float wz = lw[kt.z];
        const float ww = lw[kt.w];

        const float4 k0 = kl4[4 * g + 0];
        const float4 k1 = kl4[4 * g + 1];
        const float4 k2 = kl4[4 * g + 2];
        const float4 k3 = kl4[4 * g + 3];
        const float4 m0 = m4[3 * g + 0];
        const float4 m1 = m4[3 * g + 1];
        const float4 m2 = m4[3 * g + 2];
        const float4 l0 = l4[3 * g + 0];
        const float4 l1 = l4[3 * g + 1];
        const float4 l2 = l4[3 * g + 2];

        do_sample(k0.x, k0.y, k0.z, k0.w, m0.x, m0.y, m0.z, l0.x, l0.y, l0.z,
                  kt.x, mt.x, lt.x, wx, s0, s1, s2);
        do_sample(k1.x, k1.y, k1.z, k1.w, m0.w, m1.x, m1.y, l0.w, l1.x, l1.y,
                  kt.y, mt.y, lt.y, wy, s0, s1, s2);
        do_sample(k2.x, k2.y, k2.z, k2.w, m1.z, m1.w, m2.x, l1.z, l1.w, l2.x,
                  kt.z, mt.z, lt.z, wz, s0, s1, s2);
        do_sample(k3.x, k3.y, k3.z, k3.w, m2.y, m2.z, m2.w, l2.y, l2.z, l2.w,
                  kt.w, mt.w, lt.w, ww, s0, s1, s2);
    }

    // scalar tail (n % 4 samples; zero iterations when N % 4 == 0)
    const int tail_base = ngroups << 2;
    for (int i = tail_base + blockIdx.x * THREADS + threadIdx.x; i < n;
         i += stride) {
        do_sample(kl_logits[4 * i], kl_logits[4 * i + 1], kl_logits[4 * i + 2],
                  kl_logits[4 * i + 3],
                  jsnm_logits[3 * i], jsnm_logits[3 * i + 1], jsnm_logits[3 * i + 2],
                  jsnl_logits[3 * i], jsnl_logits[3 * i + 1], jsnl_logits[3 * i + 2],
                  kl_t[i], jsnm_t[i], jsnl_t[i], lw[kl_t[i]], s0, s1, s2);
    }

    // wave reduction (64 lanes)
    #pragma unroll
    for (int off = 32; off > 0; off >>= 1) {
        s0 += __shfl_xor(s0, off);
        s1 += __shfl_xor(s1, off);
        s2 += __shfl_xor(s2, off);
    }

    __shared__ float red[3][WAVES];
    const int lane = threadIdx.x & 63;
    const int wid  = threadIdx.x >> 6;
    if (lane == 0) {
        red[0][wid] = s0;
        red[1][wid] = s1;
        red[2][wid] = s2;
    }
    __syncthreads();
    if (threadIdx.x == 0) {
        float t0 = 0.0f, t1 = 0.0f, t2 = 0.0f;
        #pragma unroll
        for (int wv = 0; wv < WAVES; ++wv) {
            t0 += red[0][wv];
            t1 += red[1][wv];
            t2 += red[2][wv];
        }
        partials[blockIdx.x * 3 + 0] = t0;
        partials[blockIdx.x * 3 + 1] = t1;
        partials[blockIdx.x * 3 + 2] = t2;
    }
}

__global__ __launch_bounds__(THREADS) void coral_finalize(
        const float* __restrict__ partials, float* __restrict__ out,
        int nblocks, float n) {
    float s0 = 0.0f, s1 = 0.0f, s2 = 0.0f;
    for (int i = threadIdx.x; i < nblocks; i += THREADS) {
        s0 += partials[3 * i + 0];
        s1 += partials[3 * i + 1];
        s2 += partials[3 * i + 2];
    }
    #pragma unroll
    for (int off = 32; off > 0; off >>= 1) {
        s0 += __shfl_xor(s0, off);
        s1 += __shfl_xor(s1, off);
        s2 += __shfl_xor(s2, off);
    }
    __shared__ float red[3][WAVES];
    const int lane = threadIdx.x & 63;
    const int wid  = threadIdx.x >> 6;
    if (lane == 0) {
        red[0][wid] = s0;
        red[1][wid] = s1;
        red[2][wid] = s2;
    }
    __syncthreads();
    if (threadIdx.x == 0) {
        float t0 = 0.0f, t1 = 0.0f, t2 = 0.0f;
        #pragma unroll
        for (int wv = 0; wv < WAVES; ++wv) {
            t0 += red[0][wv];
            t1 += red[1][wv];
            t2 += red[2][wv];
        }
        const float l_kl   = t0 / (n * 4.0f);
        const float l_jsnm = t1 / (n * 3.0f);
        const float l_jsnl = t2 / (n * 3.0f);
        out[0] = (l_kl + l_jsnm + l_jsnl) / 3.0f;
        out[1] = l_kl;
        out[2] = l_jsnm;
        out[3] = l_jsnl;
    }
}

extern "C" void kernel_launch(void* const* d_in, const int* in_sizes, int n_in,
                              void* d_out, int out_size, void* d_ws, size_t ws_size,
                              hipStream_t stream) {
    const float* kl_logits   = (const float*)d_in[0];
    const float* jsnm_logits = (const float*)d_in[1];
    const float* jsnl_logits = (const float*)d_in[2];
    const float* cw          = (const float*)d_in[3];
    const int*   kl_t        = (const int*)d_in[4];
    const int*   jsnm_t      = (const int*)d_in[5];
    const int*   jsnl_t      = (const int*)d_in[6];
    const int n = in_sizes[4];  // kl_t element count == N

    const int ngroups = n >> 2;
    int blocks = BLOCKS;
    int max_blocks = (ngroups + THREADS - 1) / THREADS;
    if (blocks > max_blocks) blocks = max_blocks;
    if (blocks < 1) blocks = 1;

    float* partials = (float*)d_ws;   // blocks*3 floats
    float* out      = (float*)d_out;  // (total, l_kl, l_jsnm, l_jsnl)

    coral_main<<<blocks, THREADS, 0, stream>>>(
        kl_logits, jsnm_logits, jsnl_logits, cw, kl_t, jsnm_t, jsnl_t,
        partials, n, ngroups);
    coral_finalize<<<1, THREADS, 0, stream>>>(partials, out, blocks, (float)n);
}